// Round 1
// baseline (119.638 us; speedup 1.0000x reference)
//
#include <hip/hip_runtime.h>

// Problem constants (match reference).
#define B_ 4096
#define D_ 512
#define STEPS_ 50

// One wave (64 lanes) per row. Each lane owns 8 contiguous floats (two
// float4 loads at lane*16B and lane*16B+1KB). All Adam state (x, m, v)
// plus s-row and W stay in registers for all 50 steps; only the final x
// is written back. Row coupling is only the dot product x.W -> butterfly
// shuffle reduce across the 64 lanes.
__global__ __launch_bounds__(256) void adam_rows_kernel(
    const float* __restrict__ s,
    const float* __restrict__ tgt,
    const float* __restrict__ W,
    const float* __restrict__ bias_p,
    float* __restrict__ out)
{
    const int lane = threadIdx.x & 63;
    const int row  = (blockIdx.x << 2) + (threadIdx.x >> 6);

    const float4* srow4 = (const float4*)(s + (size_t)row * D_);
    const float4* W4    = (const float4*)W;

    float4 sa = srow4[lane];
    float4 sb = srow4[lane + 64];
    float4 wa = W4[lane];
    float4 wb = W4[lane + 64];
    const float b = bias_p[0];
    const float t = tgt[row];

    float xs[8] = {sa.x, sa.y, sa.z, sa.w, sb.x, sb.y, sb.z, sb.w};
    float ss[8] = {sa.x, sa.y, sa.z, sa.w, sb.x, sb.y, sb.z, sb.w};
    float ws[8] = {wa.x, wa.y, wa.z, wa.w, wb.x, wb.y, wb.z, wb.w};
    float m[8], v[8];
#pragma unroll
    for (int k = 0; k < 8; ++k) { m[k] = 0.0f; v[k] = 0.0f; }

    const float c_mse = 2.0f / (float)B_;                    // d(mse)/dp scale
    const float c_l1  = 1.0f / ((float)B_ * (float)D_);      // l1 grad scale
    float pow1 = 1.0f, pow2 = 1.0f;

    for (int step = 0; step < STEPS_; ++step) {
        // z = x . W  (row dot product)
        float z = 0.0f;
#pragma unroll
        for (int k = 0; k < 8; ++k) z = fmaf(xs[k], ws[k], z);
#pragma unroll
        for (int off = 32; off > 0; off >>= 1)
            z += __shfl_xor(z, off, 64);
        z += b;

        // p = sigmoid(z); coef = (2/B)(p-t)p(1-p)
        const float p    = __builtin_amdgcn_rcpf(1.0f + __expf(-z));
        const float coef = c_mse * (p - t) * p * (1.0f - p);

        // bias corrections for t = step+1
        pow1 *= 0.9f;
        pow2 *= 0.999f;
        const float bc1 = __builtin_amdgcn_rcpf(1.0f - pow1);
        const float bc2 = __builtin_amdgcn_rcpf(1.0f - pow2);

#pragma unroll
        for (int k = 0; k < 8; ++k) {
            const float d  = xs[k] - ss[k];
            const float sg = (d > 0.0f) ? 1.0f : ((d < 0.0f) ? -1.0f : 0.0f);
            const float g  = fmaf(coef, ws[k], sg * c_l1);
            // 0.1f / 0.001f literals: match host-side (1.0 - B1) f64->f32
            m[k] = fmaf(0.9f,   m[k], 0.1f   * g);
            v[k] = fmaf(0.999f, v[k], 0.001f * (g * g));
            const float mh  = m[k] * bc1;
            const float vh  = v[k] * bc2;
            const float den = __builtin_amdgcn_sqrtf(vh) + 1e-8f;
            xs[k] = fmaf(-0.01f * mh, __builtin_amdgcn_rcpf(den), xs[k]);
        }
    }

    float4 oa = {xs[0], xs[1], xs[2], xs[3]};
    float4 ob = {xs[4], xs[5], xs[6], xs[7]};
    float4* orow4 = (float4*)(out + (size_t)row * D_);
    orow4[lane]      = oa;
    orow4[lane + 64] = ob;
}

extern "C" void kernel_launch(void* const* d_in, const int* in_sizes, int n_in,
                              void* d_out, int out_size, void* d_ws, size_t ws_size,
                              hipStream_t stream) {
    const float* s    = (const float*)d_in[0];  // [4096, 512]
    const float* tgt  = (const float*)d_in[1];  // [4096, 1]
    const float* W    = (const float*)d_in[2];  // [1, 512]
    const float* bias = (const float*)d_in[3];  // [1]
    float* out = (float*)d_out;                 // [4096, 512]

    // 4096 rows, one wave per row, 4 waves (256 threads) per block.
    dim3 grid(B_ / 4), block(256);
    adam_rows_kernel<<<grid, block, 0, stream>>>(s, tgt, W, bias, out);
}

// Round 2
// 107.802 us; speedup vs baseline: 1.1098x; 1.1098x over previous
//
#include <hip/hip_runtime.h>

#define B_ 4096
#define D_ 512
#define STEPS_ 50

__device__ __forceinline__ float wave_reduce_add(float z) {
#pragma unroll
    for (int off = 32; off > 0; off >>= 1)
        z += __shfl_xor(z, off, 64);
    return z;
}

// One wave per row, 8 elements/lane, all Adam state register-resident.
// Track delta = x - s (not x): sign(x-s) is delta's sign bit, and
// z = x.W = (s.W) + delta.W with s.W hoisted out of the step loop.
// Rescaled state: M = 0.9M + g (m = 0.1*M), V = 0.999V + g^2 (v = 0.001*V);
// bias-correction and lr folded into per-step uniforms A, u2.
// __launch_bounds__(256,4): we only ever have 4 waves/SIMD (4096 waves
// total), so allow ~128 VGPRs — R1's bare bound gave VGPR=32 and the
// compiler round-tripped state through AGPRs (~2x dynamic instrs).
__global__ __launch_bounds__(256, 4) void adam_rows_kernel(
    const float* __restrict__ s,
    const float* __restrict__ tgt,
    const float* __restrict__ W,
    const float* __restrict__ bias_p,
    float* __restrict__ out)
{
    const int lane = threadIdx.x & 63;
    const int row  = (blockIdx.x << 2) + (threadIdx.x >> 6);

    const float4* srow4 = (const float4*)(s + (size_t)row * D_);
    const float4* W4    = (const float4*)W;

    float4 sa = srow4[lane];
    float4 sb = srow4[lane + 64];
    float4 wa = W4[lane];
    float4 wb = W4[lane + 64];
    const float b = bias_p[0];
    const float t = tgt[row];

    float ss[8] = {sa.x, sa.y, sa.z, sa.w, sb.x, sb.y, sb.z, sb.w};
    float ws[8] = {wa.x, wa.y, wa.z, wa.w, wb.x, wb.y, wb.z, wb.w};
    float dl[8], M[8], V[8];

    const float c_mse = 2.0f / (float)B_;
    const float c_l1  = 1.0f / ((float)B_ * (float)D_);
    const unsigned c_l1_bits = __float_as_uint(c_l1);

    // Row-constant part of the dot product: zs = s . W
    float zs = 0.0f;
#pragma unroll
    for (int k = 0; k < 8; ++k) zs = fmaf(ss[k], ws[k], zs);
    zs = wave_reduce_add(zs);

    float pow1 = 0.9f, pow2 = 0.999f;

    // ---- step 0 peeled: delta == 0 exactly, so sign term is 0 ----
    {
        const float z    = zs + b;
        const float p    = __builtin_amdgcn_rcpf(1.0f + __expf(-z));
        const float coef = c_mse * (p - t) * p * (1.0f - p);
        const float A  = 0.001f * __builtin_amdgcn_rcpf(1.0f - pow1); // lr*0.1*bc1
        const float u2 = 0.001f * __builtin_amdgcn_rcpf(1.0f - pow2); // 0.001*bc2
#pragma unroll
        for (int k = 0; k < 8; ++k) {
            const float g = coef * ws[k];
            M[k] = g;
            V[k] = g * g;
            const float den = __builtin_amdgcn_sqrtf(V[k] * u2) + 1e-8f;
            dl[k] = -(A * M[k]) * __builtin_amdgcn_rcpf(den);
        }
    }

    // ---- steps 1..49: delta != 0 generically; branch-free copysign L1 ----
#pragma unroll 1
    for (int step = 1; step < STEPS_; ++step) {
        float dotd = 0.0f;
#pragma unroll
        for (int k = 0; k < 8; ++k) dotd = fmaf(dl[k], ws[k], dotd);
        dotd = wave_reduce_add(dotd);

        const float z    = (zs + dotd) + b;
        const float p    = __builtin_amdgcn_rcpf(1.0f + __expf(-z));
        const float coef = c_mse * (p - t) * p * (1.0f - p);

        pow1 *= 0.9f;
        pow2 *= 0.999f;
        const float A  = 0.001f * __builtin_amdgcn_rcpf(1.0f - pow1);
        const float u2 = 0.001f * __builtin_amdgcn_rcpf(1.0f - pow2);

#pragma unroll
        for (int k = 0; k < 8; ++k) {
            const unsigned sbit = __float_as_uint(dl[k]) & 0x80000000u;
            const float gl1 = __uint_as_float(sbit | c_l1_bits);
            const float g = fmaf(coef, ws[k], gl1);
            M[k] = fmaf(0.9f,   M[k], g);
            V[k] = fmaf(0.999f, V[k], g * g);
            const float den = __builtin_amdgcn_sqrtf(V[k] * u2) + 1e-8f;
            dl[k] = fmaf(-(A * M[k]), __builtin_amdgcn_rcpf(den), dl[k]);
        }
    }

    float4 oa = {ss[0] + dl[0], ss[1] + dl[1], ss[2] + dl[2], ss[3] + dl[3]};
    float4 ob = {ss[4] + dl[4], ss[5] + dl[5], ss[6] + dl[6], ss[7] + dl[7]};
    float4* orow4 = (float4*)(out + (size_t)row * D_);
    orow4[lane]      = oa;
    orow4[lane + 64] = ob;
}

extern "C" void kernel_launch(void* const* d_in, const int* in_sizes, int n_in,
                              void* d_out, int out_size, void* d_ws, size_t ws_size,
                              hipStream_t stream) {
    const float* s    = (const float*)d_in[0];  // [4096, 512]
    const float* tgt  = (const float*)d_in[1];  // [4096, 1]
    const float* W    = (const float*)d_in[2];  // [1, 512]
    const float* bias = (const float*)d_in[3];  // [1]
    float* out = (float*)d_out;                 // [4096, 512]

    dim3 grid(B_ / 4), block(256);
    adam_rows_kernel<<<grid, block, 0, stream>>>(s, tgt, W, bias, out);
}

// Round 3
// 100.319 us; speedup vs baseline: 1.1926x; 1.0746x over previous
//
#include <hip/hip_runtime.h>

#define B_ 4096
#define D_ 512
#define STEPS_ 50

// Per-step Adam scalars, precomputed on host (pure constants -> kernel args,
// loaded via scalar pipe instead of 8 VALU ops/step).
// negA[t] = -lr*0.1/(1-0.9^(t+1));  u2[t] = 0.001/(1-0.999^(t+1))
// (state is rescaled: M = 0.9M + g so m = 0.1M; V = 0.999V + g^2 so v = 0.001V)
struct BcTab { float negA[STEPS_]; float u2[STEPS_]; };

// All-VALU wave64 sum: row_shr 1/2/4/8 prefix within rows of 16, then
// bcast15 + bcast31 accumulate across rows; lane 63 holds the total,
// readlane broadcasts it through an SGPR. Replaces the 6-deep dependent
// ds_bpermute chain (~200+ cy) of __shfl_xor with a short VALU chain.
#define DPP_ADD(x, ctrl) \
    ((x) + __int_as_float(__builtin_amdgcn_update_dpp( \
        0, __float_as_int(x), (ctrl), 0xf, 0xf, true)))

__device__ __forceinline__ float wave64_sum(float x) {
    x = DPP_ADD(x, 0x111);  // row_shr:1
    x = DPP_ADD(x, 0x112);  // row_shr:2
    x = DPP_ADD(x, 0x114);  // row_shr:4
    x = DPP_ADD(x, 0x118);  // row_shr:8  -> lane15 of each row16 = row sum
    x = DPP_ADD(x, 0x142);  // row_bcast:15 -> lane31 = R0+R1, lane63 = R2+R3
    x = DPP_ADD(x, 0x143);  // row_bcast:31 -> lane63 = total
    return __int_as_float(__builtin_amdgcn_readlane(__float_as_int(x), 63));
}

// One wave (= one 64-thread block) per row, 8 elems/lane, all state in
// registers. __launch_bounds__(64,1): register budget 512/wave so the
// allocator keeps everything in arch VGPRs — R1/R2 showed VGPR_Count=32
// with state split into AGPRs (accvgpr shuttling ~70% instr overhead).
__global__ __launch_bounds__(64, 1) void adam_rows_kernel(
    const float* __restrict__ s,
    const float* __restrict__ tgt,
    const float* __restrict__ W,
    const float* __restrict__ bias_p,
    float* __restrict__ out,
    const BcTab bc)
{
    const int lane = threadIdx.x;      // 0..63
    const int row  = blockIdx.x;       // 0..4095

    const float4* srow4 = (const float4*)(s + (size_t)row * D_);
    const float4* W4    = (const float4*)W;

    float4 sa = srow4[lane];
    float4 sb = srow4[lane + 64];
    float4 wa = W4[lane];
    float4 wb = W4[lane + 64];
    const float t = tgt[row];

    float ss[8] = {sa.x, sa.y, sa.z, sa.w, sb.x, sb.y, sb.z, sb.w};
    float ws[8] = {wa.x, wa.y, wa.z, wa.w, wb.x, wb.y, wb.z, wb.w};
    float dl[8], M[8], V[8];

    const float c_mse = 2.0f / (float)B_;
    const unsigned c_l1_bits = 0x35000000u;  // 1/(4096*512) = 2^-21

    // zb = s.W + b : row-constant part of the logit, hoisted.
    float zdot = 0.0f;
#pragma unroll
    for (int k = 0; k < 8; ++k) zdot = fmaf(ss[k], ws[k], zdot);
    const float zb = wave64_sum(zdot) + bias_p[0];

    // ---- step 0 peeled: delta == 0 exactly -> sign term is 0 ----
    {
        const float p    = __builtin_amdgcn_rcpf(1.0f + __expf(-zb));
        const float coef = c_mse * (p - t) * p * (1.0f - p);
        const float negA = bc.negA[0];
        const float u2   = bc.u2[0];
#pragma unroll
        for (int k = 0; k < 8; ++k) {
            const float g = coef * ws[k];
            M[k] = g;
            V[k] = g * g;
            const float den = __builtin_amdgcn_sqrtf(V[k] * u2) + 1e-8f;
            dl[k] = (negA * M[k]) * __builtin_amdgcn_rcpf(den);
        }
    }

    // ---- steps 1..49 ----
#pragma unroll 1
    for (int step = 1; step < STEPS_; ++step) {
        float dotd = 0.0f;
#pragma unroll
        for (int k = 0; k < 8; ++k) dotd = fmaf(dl[k], ws[k], dotd);
        const float z = zb + wave64_sum(dotd);

        const float p    = __builtin_amdgcn_rcpf(1.0f + __expf(-z));
        const float coef = c_mse * (p - t) * p * (1.0f - p);
        const float negA = bc.negA[step];  // scalar (s_load from kernarg)
        const float u2   = bc.u2[step];

#pragma unroll
        for (int k = 0; k < 8; ++k) {
            const unsigned sbit = __float_as_uint(dl[k]) & 0x80000000u;
            const float gl1 = __uint_as_float(sbit | c_l1_bits);  // sign(d)/(B*D)
            const float g = fmaf(coef, ws[k], gl1);
            M[k] = fmaf(0.9f,   M[k], g);
            V[k] = fmaf(0.999f, V[k], g * g);
            const float den = __builtin_amdgcn_sqrtf(V[k] * u2) + 1e-8f;
            dl[k] = fmaf(negA * M[k], __builtin_amdgcn_rcpf(den), dl[k]);
        }
    }

    float4 oa = {ss[0] + dl[0], ss[1] + dl[1], ss[2] + dl[2], ss[3] + dl[3]};
    float4 ob = {ss[4] + dl[4], ss[5] + dl[5], ss[6] + dl[6], ss[7] + dl[7]};
    float4* orow4 = (float4*)(out + (size_t)row * D_);
    orow4[lane]      = oa;
    orow4[lane + 64] = ob;
}

extern "C" void kernel_launch(void* const* d_in, const int* in_sizes, int n_in,
                              void* d_out, int out_size, void* d_ws, size_t ws_size,
                              hipStream_t stream) {
    const float* s    = (const float*)d_in[0];  // [4096, 512]
    const float* tgt  = (const float*)d_in[1];  // [4096, 1]
    const float* W    = (const float*)d_in[2];  // [1, 512]
    const float* bias = (const float*)d_in[3];  // [1]
    float* out = (float*)d_out;                 // [4096, 512]

    BcTab bc;
    double p1 = 1.0, p2 = 1.0;
    for (int t = 0; t < STEPS_; ++t) {
        p1 *= 0.9; p2 *= 0.999;
        bc.negA[t] = (float)(-0.001 / (1.0 - p1));
        bc.u2[t]   = (float)( 0.001 / (1.0 - p2));
    }

    adam_rows_kernel<<<dim3(B_), dim3(64), 0, stream>>>(s, tgt, W, bias, out, bc);
}

// Round 4
// 99.659 us; speedup vs baseline: 1.2005x; 1.0066x over previous
//
#include <hip/hip_runtime.h>

#define B_ 4096
#define D_ 512
#define STEPS_ 50

// Host-precomputed per-step Adam scalars (scalar-pipe loads, off the VALU).
// State is rescaled: M = 0.9M + g (m = 0.1M), V = 0.999V + g^2 (v = 0.001V).
// negA[t]  = -lr*0.1/(1-0.9^(t+1))
// sqU2[t]  = sqrt(0.001/(1-0.999^(t+1)))   (so sqrt(v_hat) = sqU2*sqrt(V))
struct BcTab { float negA[STEPS_]; float sqU2[STEPS_]; };

// All-VALU wave64 sum via DPP; lane63 accumulates total, readlane -> SGPR.
#define DPP_ADD(x, ctrl) \
    ((x) + __int_as_float(__builtin_amdgcn_update_dpp( \
        0, __float_as_int(x), (ctrl), 0xf, 0xf, true)))

__device__ __forceinline__ float wave64_sum(float x) {
    x = DPP_ADD(x, 0x111);  // row_shr:1
    x = DPP_ADD(x, 0x112);  // row_shr:2
    x = DPP_ADD(x, 0x114);  // row_shr:4
    x = DPP_ADD(x, 0x118);  // row_shr:8
    x = DPP_ADD(x, 0x142);  // row_bcast:15
    x = DPP_ADD(x, 0x143);  // row_bcast:31
    return __int_as_float(__builtin_amdgcn_readlane(__float_as_int(x), 63));
}

// copysign(c_l1, d) via single bitfield-insert-shaped expression.
__device__ __forceinline__ float sgn_l1(float d) {
    const unsigned c_l1_bits = 0x35000000u;  // 1/(4096*512) = 2^-21
    return __uint_as_float((__float_as_uint(d) & 0x80000000u) | c_l1_bits);
}

// One wave (= one 64-thread block) per row; 8 elems/lane as float2[4] so
// the SLP vectorizer can form v_pk_{fma,mul,add}_f32 (dual-issue f32x2).
// dl tracks x - s; z = (s.W + b) + dl.W; the dl.W dot for step t+1 is
// accumulated inside step t's element loop (du), so each step's serial
// region is just DPP-reduce + sigmoid chain.
__global__ __launch_bounds__(64, 1) void adam_rows_kernel(
    const float* __restrict__ s,
    const float* __restrict__ tgt,
    const float* __restrict__ W,
    const float* __restrict__ bias_p,
    float* __restrict__ out,
    const BcTab bc)
{
    const int lane = threadIdx.x;      // 0..63
    const int row  = blockIdx.x;       // 0..4095

    const float4* srow4 = (const float4*)(s + (size_t)row * D_);
    const float4* W4    = (const float4*)W;

    float4 sa = srow4[lane];
    float4 sb = srow4[lane + 64];
    float4 wa = W4[lane];
    float4 wb = W4[lane + 64];
    const float t = tgt[row];

    float2 ss[4] = {{sa.x, sa.y}, {sa.z, sa.w}, {sb.x, sb.y}, {sb.z, sb.w}};
    float2 ws[4] = {{wa.x, wa.y}, {wa.z, wa.w}, {wb.x, wb.y}, {wb.z, wb.w}};
    float2 dl[4], M[4], V[4];

    const float c_mse = 2.0f / (float)B_;

    // zb = s.W + b (row-constant), two accumulator chains then DPP reduce.
    float za = 0.0f, zc = 0.0f;
#pragma unroll
    for (int j = 0; j < 4; ++j) {
        za = fmaf(ss[j].x, ws[j].x, za);
        zc = fmaf(ss[j].y, ws[j].y, zc);
    }
    const float zb = wave64_sum(za + zc) + bias_p[0];

    float du;  // dl.W partial for the NEXT step, accumulated in-loop

    // ---- step 0 peeled: dl == 0 exactly -> L1 term is 0 ----
    {
        const float p    = __builtin_amdgcn_rcpf(1.0f + __expf(-zb));
        const float coef = c_mse * (p - t) * p * (1.0f - p);
        const float negA = bc.negA[0];
        const float squ2 = bc.sqU2[0];
        float dua = 0.0f, dub = 0.0f;
#pragma unroll
        for (int j = 0; j < 4; ++j) {
            const float gx = coef * ws[j].x;
            const float gy = coef * ws[j].y;
            M[j].x = gx;                 M[j].y = gy;
            V[j].x = gx * gx;            V[j].y = gy * gy;
            const float dnx = fmaf(squ2, __builtin_amdgcn_sqrtf(V[j].x), 1e-8f);
            const float dny = fmaf(squ2, __builtin_amdgcn_sqrtf(V[j].y), 1e-8f);
            dl[j].x = (negA * M[j].x) * __builtin_amdgcn_rcpf(dnx);
            dl[j].y = (negA * M[j].y) * __builtin_amdgcn_rcpf(dny);
            dua = fmaf(dl[j].x, ws[j].x, dua);
            dub = fmaf(dl[j].y, ws[j].y, dub);
        }
        du = dua + dub;
    }

    // ---- steps 1..49 ----
#pragma unroll 1
    for (int step = 1; step < STEPS_; ++step) {
        const float z    = zb + wave64_sum(du);
        const float p    = __builtin_amdgcn_rcpf(1.0f + __expf(-z));
        const float coef = c_mse * (p - t) * p * (1.0f - p);
        const float negA = bc.negA[step];
        const float squ2 = bc.sqU2[step];

        float dua = 0.0f, dub = 0.0f;
#pragma unroll
        for (int j = 0; j < 4; ++j) {
            const float gx = fmaf(coef, ws[j].x, sgn_l1(dl[j].x));
            const float gy = fmaf(coef, ws[j].y, sgn_l1(dl[j].y));
            M[j].x = fmaf(0.9f,   M[j].x, gx);
            M[j].y = fmaf(0.9f,   M[j].y, gy);
            V[j].x = fmaf(0.999f, V[j].x, gx * gx);
            V[j].y = fmaf(0.999f, V[j].y, gy * gy);
            const float dnx = fmaf(squ2, __builtin_amdgcn_sqrtf(V[j].x), 1e-8f);
            const float dny = fmaf(squ2, __builtin_amdgcn_sqrtf(V[j].y), 1e-8f);
            dl[j].x = fmaf(negA * M[j].x, __builtin_amdgcn_rcpf(dnx), dl[j].x);
            dl[j].y = fmaf(negA * M[j].y, __builtin_amdgcn_rcpf(dny), dl[j].y);
            dua = fmaf(dl[j].x, ws[j].x, dua);
            dub = fmaf(dl[j].y, ws[j].y, dub);
        }
        du = dua + dub;
    }

    float4 oa = {ss[0].x + dl[0].x, ss[0].y + dl[0].y,
                 ss[1].x + dl[1].x, ss[1].y + dl[1].y};
    float4 ob = {ss[2].x + dl[2].x, ss[2].y + dl[2].y,
                 ss[3].x + dl[3].x, ss[3].y + dl[3].y};
    float4* orow4 = (float4*)(out + (size_t)row * D_);
    orow4[lane]      = oa;
    orow4[lane + 64] = ob;
}

extern "C" void kernel_launch(void* const* d_in, const int* in_sizes, int n_in,
                              void* d_out, int out_size, void* d_ws, size_t ws_size,
                              hipStream_t stream) {
    const float* s    = (const float*)d_in[0];  // [4096, 512]
    const float* tgt  = (const float*)d_in[1];  // [4096, 1]
    const float* W    = (const float*)d_in[2];  // [1, 512]
    const float* bias = (const float*)d_in[3];  // [1]
    float* out = (float*)d_out;                 // [4096, 512]

    BcTab bc;
    double p1 = 1.0, p2 = 1.0;
    for (int t = 0; t < STEPS_; ++t) {
        p1 *= 0.9; p2 *= 0.999;
        bc.negA[t] = (float)(-0.001 / (1.0 - p1));
        bc.sqU2[t] = (float)__builtin_sqrt(0.001 / (1.0 - p2));
    }

    adam_rows_kernel<<<dim3(B_), dim3(64), 0, stream>>>(s, tgt, W, bias, out, bc);
}

// Round 5
// 96.659 us; speedup vs baseline: 1.2377x; 1.0310x over previous
//
#include <hip/hip_runtime.h>

#define B_ 4096
#define D_ 512
#define STEPS_ 50

// Host-precomputed per-step scalar. With rescaled state M = 0.9M + g
// (m = 0.1M) and V = 0.999V + g^2 (v = 0.001V), and eps dropped:
//   update = -lr*mhat/sqrt(vhat) = An[t] * M * rsq(V)
//   An[t]  = -(lr*0.1/(1-0.9^(t+1))) / sqrt(0.001/(1-0.999^(t+1)))
struct BcTab { float An[STEPS_]; };

// All-VALU wave64 sum via DPP; lane63 holds total, readlane -> SGPR.
#define DPP_ADD(x, ctrl) \
    ((x) + __int_as_float(__builtin_amdgcn_update_dpp( \
        0, __float_as_int(x), (ctrl), 0xf, 0xf, true)))

__device__ __forceinline__ float wave64_sum(float x) {
    x = DPP_ADD(x, 0x111);  // row_shr:1
    x = DPP_ADD(x, 0x112);  // row_shr:2
    x = DPP_ADD(x, 0x114);  // row_shr:4
    x = DPP_ADD(x, 0x118);  // row_shr:8
    x = DPP_ADD(x, 0x142);  // row_bcast:15
    x = DPP_ADD(x, 0x143);  // row_bcast:31
    return __int_as_float(__builtin_amdgcn_readlane(__float_as_int(x), 63));
}

// copysign(1/(B*D), d): sign bit of d merged onto 2^-21 (v_bfi).
__device__ __forceinline__ float sgn_l1(float d) {
    return __uint_as_float((__float_as_uint(d) & 0x80000000u) | 0x35000000u);
}

// coef' = (p - t) * p * (1 - p) with p = sigmoid(z); p(1-p) = e*p^2, e=exp(-z).
// (The 2/B factor is pre-folded into the W copy each lane holds.)
__device__ __forceinline__ float coef_from_z(float z, float t) {
    const float e = __expf(-z);
    const float q = __builtin_amdgcn_rcpf(1.0f + e);
    return (q - t) * (e * (q * q));
}

// TWO rows per wave (W shared): the two rows' per-step serial chains
// (DPP reduce + sigmoid) are independent and interleave within the wave,
// filling the issue gaps that made R4 sit at 67% VALUBusy with 4
// phase-locked waves/SIMD. 2048 waves = 2/SIMD; latency hiding comes from
// 16 independent per-element chains + 2 independent serial chains per wave.
// eps dropped: update = An * M * rsq(max(V,1e-37)); clamp makes the
// all-zero-gradient row give update 0 (matches reference 0/(0+eps)=0).
__global__ __launch_bounds__(64, 1) void adam_rows_kernel(
    const float* __restrict__ s,
    const float* __restrict__ tgt,
    const float* __restrict__ W,
    const float* __restrict__ bias_p,
    float* __restrict__ out,
    const BcTab bc)
{
    const int lane = threadIdx.x;          // 0..63
    const int r0 = blockIdx.x * 2;
    const int r1 = r0 + 1;

    const float4* s0 = (const float4*)(s + (size_t)r0 * D_);
    const float4* s1 = (const float4*)(s + (size_t)r1 * D_);
    const float4* W4 = (const float4*)W;

    float4 sa0 = s0[lane], sb0 = s0[lane + 64];
    float4 sa1 = s1[lane], sb1 = s1[lane + 64];
    float4 wa  = W4[lane], wb  = W4[lane + 64];
    const float t0 = tgt[r0], t1 = tgt[r1];
    const float b  = bias_p[0];

    const float c_mse = 2.0f / (float)B_;
    const float K     = (float)B_ * 0.5f;      // 1/c_mse, exact (2048)

    float2 ws[4] = {{wa.x * c_mse, wa.y * c_mse}, {wa.z * c_mse, wa.w * c_mse},
                    {wb.x * c_mse, wb.y * c_mse}, {wb.z * c_mse, wb.w * c_mse}};
    float2 ss0[4] = {{sa0.x, sa0.y}, {sa0.z, sa0.w}, {sb0.x, sb0.y}, {sb0.z, sb0.w}};
    float2 ss1[4] = {{sa1.x, sa1.y}, {sa1.z, sa1.w}, {sb1.x, sb1.y}, {sb1.z, sb1.w}};
    float2 dl0[4], dl1[4], M0[4], M1[4], V0[4], V1[4];

    // zb_r = s_r.W + b (scaled dot recovered via K)
    float za0 = 0.0f, za1 = 0.0f;
#pragma unroll
    for (int j = 0; j < 4; ++j) {
        za0 = fmaf(ss0[j].x, ws[j].x, za0); za0 = fmaf(ss0[j].y, ws[j].y, za0);
        za1 = fmaf(ss1[j].x, ws[j].x, za1); za1 = fmaf(ss1[j].y, ws[j].y, za1);
    }
    const float zb0 = fmaf(K, wave64_sum(za0), b);
    const float zb1 = fmaf(K, wave64_sum(za1), b);

    float du0, du1;  // scaled dl.W partials for the NEXT step

    // ---- step 0 peeled: dl == 0 -> L1 term is 0; update = -lr*sign(g) ----
    {
        const float c0 = coef_from_z(zb0, t0);
        const float c1 = coef_from_z(zb1, t1);
        const float An = bc.An[0];
        float a0 = 0.0f, a1 = 0.0f;
#pragma unroll
        for (int j = 0; j < 4; ++j) {
#pragma unroll
            for (int h = 0; h < 2; ++h) {
                float* w_  = h ? &ws[j].y  : &ws[j].x;
                float* m0_ = h ? &M0[j].y  : &M0[j].x;
                float* v0_ = h ? &V0[j].y  : &V0[j].x;
                float* d0_ = h ? &dl0[j].y : &dl0[j].x;
                float* m1_ = h ? &M1[j].y  : &M1[j].x;
                float* v1_ = h ? &V1[j].y  : &V1[j].x;
                float* d1_ = h ? &dl1[j].y : &dl1[j].x;
                const float g0 = c0 * *w_;
                const float g1 = c1 * *w_;
                *m0_ = g0; *v0_ = g0 * g0;
                *m1_ = g1; *v1_ = g1 * g1;
                const float r0r = __builtin_amdgcn_rsqf(fmaxf(*v0_, 1e-37f));
                const float r1r = __builtin_amdgcn_rsqf(fmaxf(*v1_, 1e-37f));
                *d0_ = (An * *m0_) * r0r;
                *d1_ = (An * *m1_) * r1r;
                a0 = fmaf(*d0_, *w_, a0);
                a1 = fmaf(*d1_, *w_, a1);
            }
        }
        du0 = a0; du1 = a1;
    }

    // ---- steps 1..49 ----
#pragma unroll 1
    for (int step = 1; step < STEPS_; ++step) {
        const float z0 = fmaf(K, wave64_sum(du0), zb0);
        const float z1 = fmaf(K, wave64_sum(du1), zb1);
        const float c0 = coef_from_z(z0, t0);
        const float c1 = coef_from_z(z1, t1);
        const float An = bc.An[step];

        float a0 = 0.0f, a1 = 0.0f;
#pragma unroll
        for (int j = 0; j < 4; ++j) {
#pragma unroll
            for (int h = 0; h < 2; ++h) {
                float* w_  = h ? &ws[j].y  : &ws[j].x;
                float* m0_ = h ? &M0[j].y  : &M0[j].x;
                float* v0_ = h ? &V0[j].y  : &V0[j].x;
                float* d0_ = h ? &dl0[j].y : &dl0[j].x;
                float* m1_ = h ? &M1[j].y  : &M1[j].x;
                float* v1_ = h ? &V1[j].y  : &V1[j].x;
                float* d1_ = h ? &dl1[j].y : &dl1[j].x;
                const float g0 = fmaf(c0, *w_, sgn_l1(*d0_));
                const float g1 = fmaf(c1, *w_, sgn_l1(*d1_));
                *m0_ = fmaf(0.9f, *m0_, g0);
                *m1_ = fmaf(0.9f, *m1_, g1);
                *v0_ = fmaf(0.999f, *v0_, g0 * g0);
                *v1_ = fmaf(0.999f, *v1_, g1 * g1);
                const float r0r = __builtin_amdgcn_rsqf(fmaxf(*v0_, 1e-37f));
                const float r1r = __builtin_amdgcn_rsqf(fmaxf(*v1_, 1e-37f));
                *d0_ = fmaf(An * *m0_, r0r, *d0_);
                *d1_ = fmaf(An * *m1_, r1r, *d1_);
                a0 = fmaf(*d0_, *w_, a0);
                a1 = fmaf(*d1_, *w_, a1);
            }
        }
        du0 = a0; du1 = a1;
    }

    float4 oa0 = {ss0[0].x + dl0[0].x, ss0[0].y + dl0[0].y,
                  ss0[1].x + dl0[1].x, ss0[1].y + dl0[1].y};
    float4 ob0 = {ss0[2].x + dl0[2].x, ss0[2].y + dl0[2].y,
                  ss0[3].x + dl0[3].x, ss0[3].y + dl0[3].y};
    float4 oa1 = {ss1[0].x + dl1[0].x, ss1[0].y + dl1[0].y,
                  ss1[1].x + dl1[1].x, ss1[1].y + dl1[1].y};
    float4 ob1 = {ss1[2].x + dl1[2].x, ss1[2].y + dl1[2].y,
                  ss1[3].x + dl1[3].x, ss1[3].y + dl1[3].y};
    float4* o0 = (float4*)(out + (size_t)r0 * D_);
    float4* o1 = (float4*)(out + (size_t)r1 * D_);
    o0[lane] = oa0; o0[lane + 64] = ob0;
    o1[lane] = oa1; o1[lane + 64] = ob1;
}

extern "C" void kernel_launch(void* const* d_in, const int* in_sizes, int n_in,
                              void* d_out, int out_size, void* d_ws, size_t ws_size,
                              hipStream_t stream) {
    const float* s    = (const float*)d_in[0];  // [4096, 512]
    const float* tgt  = (const float*)d_in[1];  // [4096, 1]
    const float* W    = (const float*)d_in[2];  // [1, 512]
    const float* bias = (const float*)d_in[3];  // [1]
    float* out = (float*)d_out;                 // [4096, 512]

    BcTab bc;
    double p1 = 1.0, p2 = 1.0;
    for (int t = 0; t < STEPS_; ++t) {
        p1 *= 0.9; p2 *= 0.999;
        bc.An[t] = (float)((-0.001 / (1.0 - p1)) /
                           __builtin_sqrt(0.001 / (1.0 - p2)));
    }

    adam_rows_kernel<<<dim3(B_ / 2), dim3(64), 0, stream>>>(s, tgt, W, bias, out, bc);
}

// Round 6
// 93.067 us; speedup vs baseline: 1.2855x; 1.0386x over previous
//
#include <hip/hip_runtime.h>

#define B_ 4096
#define D_ 512
#define STEPS_ 50

// Host-precomputed per-step scalar. Rescaled state M = 0.9M + g (m = 0.1M),
// V = 0.999V + g^2 (v = 0.001V), eps dropped:
//   update = An[t] * M * rsq(V)
//   An[t]  = -(lr*0.1/(1-0.9^(t+1))) / sqrt(0.001/(1-0.999^(t+1)))
struct BcTab { float An[STEPS_]; };

// All-VALU wave64 sum via DPP; lane63 holds total, readlane -> SGPR.
#define DPP_ADD(x, ctrl) \
    ((x) + __int_as_float(__builtin_amdgcn_update_dpp( \
        0, __float_as_int(x), (ctrl), 0xf, 0xf, true)))

__device__ __forceinline__ float wave64_sum(float x) {
    x = DPP_ADD(x, 0x111);  // row_shr:1
    x = DPP_ADD(x, 0x112);  // row_shr:2
    x = DPP_ADD(x, 0x114);  // row_shr:4
    x = DPP_ADD(x, 0x118);  // row_shr:8
    x = DPP_ADD(x, 0x142);  // row_bcast:15
    x = DPP_ADD(x, 0x143);  // row_bcast:31
    return __int_as_float(__builtin_amdgcn_readlane(__float_as_int(x), 63));
}

// coef' = (p - t) * p * (1 - p), p = sigmoid(z); p(1-p) = e*p^2 with e=exp(-z).
// (2/B is pre-folded into ws; z recovered via K = B/2.)
__device__ __forceinline__ float coef_from_z(float z, float t) {
    const float e = __expf(-z);
    const float q = __builtin_amdgcn_rcpf(1.0f + e);
    return (q - t) * (e * (q * q));
}

// Two rows per wave, 8 elems/lane each, all state in registers.
// SOFTWARE-PIPELINED (rotated): per step, row1's reduce+sigmoid chain is
// issued alongside row0's element loop, and row0's NEXT-step chain
// alongside row1's element loop (loop-carried c0). R5 put both serial
// chains in a bubble after the joint element loop — with phase-locked
// waves nothing filled it. This hides the serial latency within the wave.
__global__ __launch_bounds__(64, 1) void adam_rows_kernel(
    const float* __restrict__ s,
    const float* __restrict__ tgt,
    const float* __restrict__ W,
    const float* __restrict__ bias_p,
    float* __restrict__ out,
    const BcTab bc)
{
    const int lane = threadIdx.x;          // 0..63
    const int r0 = blockIdx.x * 2;
    const int r1 = r0 + 1;

    const float4* s0 = (const float4*)(s + (size_t)r0 * D_);
    const float4* s1 = (const float4*)(s + (size_t)r1 * D_);
    const float4* W4 = (const float4*)W;

    const float4 wa = W4[lane], wb = W4[lane + 64];
    const float t0 = tgt[r0], t1 = tgt[r1];
    const float b  = bias_p[0];

    const float c_mse = 0x1p-11f;          // 2/B = 2^-11, exact scale of W
    const float K     = 2048.0f;           // 1/c_mse
    const float c_l1  = 0x1p-21f;          // 1/(B*D)

    float ws[8] = {wa.x * c_mse, wa.y * c_mse, wa.z * c_mse, wa.w * c_mse,
                   wb.x * c_mse, wb.y * c_mse, wb.z * c_mse, wb.w * c_mse};

    float dl0[8], dl1[8], M0[8], M1[8], V0[8], V1[8];

    // zb_r = s_r.W + b ; s rows are loaded, consumed, and not kept live.
    float zb0, zb1;
    {
        const float4 sa0 = s0[lane], sb0 = s0[lane + 64];
        const float4 sa1 = s1[lane], sb1 = s1[lane + 64];
        const float e0[8] = {sa0.x, sa0.y, sa0.z, sa0.w, sb0.x, sb0.y, sb0.z, sb0.w};
        const float e1[8] = {sa1.x, sa1.y, sa1.z, sa1.w, sb1.x, sb1.y, sb1.z, sb1.w};
        float za0 = 0.0f, za1 = 0.0f;
#pragma unroll
        for (int k = 0; k < 8; ++k) {
            za0 = fmaf(e0[k], ws[k], za0);
            za1 = fmaf(e1[k], ws[k], za1);
        }
        zb0 = fmaf(K, wave64_sum(za0), b);
        zb1 = fmaf(K, wave64_sum(za1), b);
    }

    float du0, du1;   // scaled dl.W partial sums feeding the next step

    // ---- step 0 peeled: dl == 0 -> L1 term 0. V seeded +1e-30 so V > 0
    // forever (0.999^50 * 1e-30 > 1e-31) -> no per-step max() needed.
    {
        const float c0 = coef_from_z(zb0, t0);
        const float c1 = coef_from_z(zb1, t1);
        const float An = bc.An[0];
        float a0 = 0.0f, a1 = 0.0f;
#pragma unroll
        for (int k = 0; k < 8; ++k) {
            const float g0 = c0 * ws[k];
            const float g1 = c1 * ws[k];
            M0[k] = g0;  V0[k] = fmaf(g0, g0, 1e-30f);
            M1[k] = g1;  V1[k] = fmaf(g1, g1, 1e-30f);
            dl0[k] = (An * M0[k]) * __builtin_amdgcn_rsqf(V0[k]);
            dl1[k] = (An * M1[k]) * __builtin_amdgcn_rsqf(V1[k]);
            a0 = fmaf(dl0[k], ws[k], a0);
            a1 = fmaf(dl1[k], ws[k], a1);
        }
        du0 = a0; du1 = a1;
    }

    // c0 for step 1, computed ahead (pipeline prologue).
    float c0 = coef_from_z(fmaf(K, wave64_sum(du0), zb0), t0);

    // ---- steps 1..49, rotated pipeline ----
#pragma unroll 1
    for (int step = 1; step < STEPS_; ++step) {
        const float An = bc.An[step];

        // row1 serial for THIS step: independent of row0's element loop
        // below -> issues in its shadow.
        const float c1 = coef_from_z(fmaf(K, wave64_sum(du1), zb1), t1);

        // row0 elements (uses loop-carried c0)
        float a0 = 0.0f;
#pragma unroll
        for (int k = 0; k < 8; ++k) {
            const float g = fmaf(c0, ws[k], __builtin_copysignf(c_l1, dl0[k]));
            M0[k] = fmaf(0.9f,   M0[k], g);
            V0[k] = fmaf(0.999f, V0[k], g * g);
            dl0[k] = fmaf(An * M0[k], __builtin_amdgcn_rsqf(V0[k]), dl0[k]);
            a0 = fmaf(dl0[k], ws[k], a0);
        }
        du0 = a0;

        // row0 serial for NEXT step: overlaps row1's element loop.
        c0 = coef_from_z(fmaf(K, wave64_sum(du0), zb0), t0);

        // row1 elements
        float a1 = 0.0f;
#pragma unroll
        for (int k = 0; k < 8; ++k) {
            const float g = fmaf(c1, ws[k], __builtin_copysignf(c_l1, dl1[k]));
            M1[k] = fmaf(0.9f,   M1[k], g);
            V1[k] = fmaf(0.999f, V1[k], g * g);
            dl1[k] = fmaf(An * M1[k], __builtin_amdgcn_rsqf(V1[k]), dl1[k]);
            a1 = fmaf(dl1[k], ws[k], a1);
        }
        du1 = a1;
    }

    // Epilogue: re-load s (kept out of registers for 50 steps) and add dl.
    {
        const float4 sa0 = s0[lane], sb0 = s0[lane + 64];
        const float4 sa1 = s1[lane], sb1 = s1[lane + 64];
        float4 oa0 = {sa0.x + dl0[0], sa0.y + dl0[1], sa0.z + dl0[2], sa0.w + dl0[3]};
        float4 ob0 = {sb0.x + dl0[4], sb0.y + dl0[5], sb0.z + dl0[6], sb0.w + dl0[7]};
        float4 oa1 = {sa1.x + dl1[0], sa1.y + dl1[1], sa1.z + dl1[2], sa1.w + dl1[3]};
        float4 ob1 = {sb1.x + dl1[4], sb1.y + dl1[5], sb1.z + dl1[6], sb1.w + dl1[7]};
        float4* o0 = (float4*)(out + (size_t)r0 * D_);
        float4* o1 = (float4*)(out + (size_t)r1 * D_);
        o0[lane] = oa0; o0[lane + 64] = ob0;
        o1[lane] = oa1; o1[lane + 64] = ob1;
    }
}

extern "C" void kernel_launch(void* const* d_in, const int* in_sizes, int n_in,
                              void* d_out, int out_size, void* d_ws, size_t ws_size,
                              hipStream_t stream) {
    const float* s    = (const float*)d_in[0];  // [4096, 512]
    const float* tgt  = (const float*)d_in[1];  // [4096, 1]
    const float* W    = (const float*)d_in[2];  // [1, 512]
    const float* bias = (const float*)d_in[3];  // [1]
    float* out = (float*)d_out;                 // [4096, 512]

    BcTab bc;
    double p1 = 1.0, p2 = 1.0;
    for (int t = 0; t < STEPS_; ++t) {
        p1 *= 0.9; p2 *= 0.999;
        bc.An[t] = (float)((-0.001 / (1.0 - p1)) /
                           __builtin_sqrt(0.001 / (1.0 - p2)));
    }

    adam_rows_kernel<<<dim3(B_ / 2), dim3(64), 0, stream>>>(s, tgt, W, bias, out, bc);
}

// Round 7
// 92.496 us; speedup vs baseline: 1.2934x; 1.0062x over previous
//
#include <hip/hip_runtime.h>

#define B_ 4096
#define D_ 512
#define STEPS_ 50

// All-VALU wave64 sum via DPP; lane63 holds total, readlane -> uniform.
#define DPP_ADD(x, ctrl) \
    ((x) + __int_as_float(__builtin_amdgcn_update_dpp( \
        0, __float_as_int(x), (ctrl), 0xf, 0xf, true)))

__device__ __forceinline__ float wave64_sum(float x) {
    x = DPP_ADD(x, 0x111);  // row_shr:1
    x = DPP_ADD(x, 0x112);  // row_shr:2
    x = DPP_ADD(x, 0x114);  // row_shr:4
    x = DPP_ADD(x, 0x118);  // row_shr:8
    x = DPP_ADD(x, 0x142);  // row_bcast:15
    x = DPP_ADD(x, 0x143);  // row_bcast:31
    return __int_as_float(__builtin_amdgcn_readlane(__float_as_int(x), 63));
}

// coef = (p - t) * p * (1 - p), p = sigmoid(z); p(1-p) = e*p^2, e = exp(-z).
// (2/B is pre-folded into ws; z recovered via K = B/2.)
__device__ __forceinline__ float coef_from_z(float z, float t) {
    const float e = __expf(-z);
    const float q = __builtin_amdgcn_rcpf(1.0f + e);
    return (q - t) * (e * (q * q));
}

// FOUR rows per wave (1024 waves, 1 wave/SIMD), 8 elems/lane/row, all state
// in registers. 4-way ROTATED pipeline: each row's reduce+sigmoid chain
// (DPP tree + exp/rcp, ~150-250 cy latency) is issued immediately after its
// element loop and its result is not consumed until >= 3 other rows'
// element loops (~576 cy of independent issue) have passed — deterministic
// within-wave latency hiding. R4 (4 TLP, no rotation) idled 33%; R6
// (2 TLP, 2-way rotation) ~45%: phase-locked waves can't fill the chains.
// Per-step Adam scalar An[t] is computed ONCE into a lane-indexed VGPR
// table (lane t holds An[t]) and read per step via v_readlane — no
// per-step kernarg s_load in the K-loop.
//   An[t] = -(lr*0.1/(1-0.9^(t+1))) / sqrt(0.001/(1-0.999^(t+1)))
//         = -sqrt(0.001) * sqrt(1-0.999^(t+1)) / (1-0.9^(t+1))
__global__ __launch_bounds__(64, 1) void adam_rows_kernel(
    const float* __restrict__ s,
    const float* __restrict__ tgt,
    const float* __restrict__ W,
    const float* __restrict__ bias_p,
    float* __restrict__ out)
{
    const int lane = threadIdx.x;          // 0..63
    const int rb = blockIdx.x * 4;

    // Lane-indexed An table (lanes >= 50 hold junk, never read).
    float vAn;
    {
        const float t1 = (float)(lane + 1);
        const float p1 = exp2f(t1 * -0.15200309344505f);    // 0.9^(t+1)
        const float p2 = exp2f(t1 * -0.00144345345258f);    // 0.999^(t+1)
        vAn = (-0.0316227766017f * __builtin_amdgcn_sqrtf(1.0f - p2)) *
              __builtin_amdgcn_rcpf(1.0f - p1);
    }

    const float4* W4 = (const float4*)W;
    const float4 wa = W4[lane], wb = W4[lane + 64];
    const float b = bias_p[0];

    const float c_mse = 0x1p-11f;          // 2/B, exact
    const float K     = 2048.0f;           // 1/c_mse
    const float c_l1  = 0x1p-21f;          // 1/(B*D)

    float ws[8] = {wa.x * c_mse, wa.y * c_mse, wa.z * c_mse, wa.w * c_mse,
                   wb.x * c_mse, wb.y * c_mse, wb.z * c_mse, wb.w * c_mse};

    float M[4][8], V[4][8], dl[4][8];
    float du[4], zb[4], tg[4], c[4];

    // Preamble: zb[r] = s_r.W + b (s rows loaded, consumed, not kept live).
#pragma unroll
    for (int r = 0; r < 4; ++r) {
        const float4* sr = (const float4*)(s + (size_t)(rb + r) * D_);
        const float4 sa = sr[lane], sb = sr[lane + 64];
        tg[r] = tgt[rb + r];
        const float e[8] = {sa.x, sa.y, sa.z, sa.w, sb.x, sb.y, sb.z, sb.w};
        float za = 0.0f;
#pragma unroll
        for (int k = 0; k < 8; ++k) za = fmaf(e[k], ws[k], za);
        zb[r] = fmaf(K, wave64_sum(za), b);
    }

    // ---- step 0 peeled: dl == 0 -> L1 term 0. V seeded +1e-30 so V > 0
    // forever (0.999^50 * 1e-30 > 1e-31) -> rsq never sees 0.
    {
        const float An0 =
            __int_as_float(__builtin_amdgcn_readlane(__float_as_int(vAn), 0));
#pragma unroll
        for (int r = 0; r < 4; ++r) {
            const float cr = coef_from_z(zb[r], tg[r]);
            float a = 0.0f;
#pragma unroll
            for (int k = 0; k < 8; ++k) {
                const float g = cr * ws[k];
                M[r][k] = g;
                V[r][k] = fmaf(g, g, 1e-30f);
                dl[r][k] = (An0 * g) * __builtin_amdgcn_rsqf(V[r][k]);
                a = fmaf(dl[r][k], ws[k], a);
            }
            du[r] = a;
        }
    }

    // Pipeline prologue: step-1 coefs for rows 0..2 (row 3's chain lives
    // at the loop top so it is always followed in-body by rows 0..2).
    c[0] = coef_from_z(fmaf(K, wave64_sum(du[0]), zb[0]), tg[0]);
    c[1] = coef_from_z(fmaf(K, wave64_sum(du[1]), zb[1]), tg[1]);
    c[2] = coef_from_z(fmaf(K, wave64_sum(du[2]), zb[2]), tg[2]);

    // ---- steps 1..49, 4-way rotated pipeline ----
#pragma unroll 1
    for (int step = 1; step < STEPS_; ++step) {
        const float An =
            __int_as_float(__builtin_amdgcn_readlane(__float_as_int(vAn), step));

        // Row 3's chain for THIS step: overlaps rows 0..2's element loops.
        c[3] = coef_from_z(fmaf(K, wave64_sum(du[3]), zb[3]), tg[3]);

#pragma unroll
        for (int r = 0; r < 4; ++r) {
            float a = 0.0f;
#pragma unroll
            for (int k = 0; k < 8; ++k) {
                const float g =
                    fmaf(c[r], ws[k], __builtin_copysignf(c_l1, dl[r][k]));
                M[r][k] = fmaf(0.9f,   M[r][k], g);
                V[r][k] = fmaf(0.999f, V[r][k], g * g);
                dl[r][k] =
                    fmaf(An * M[r][k], __builtin_amdgcn_rsqf(V[r][k]), dl[r][k]);
                a = fmaf(dl[r][k], ws[k], a);
            }
            du[r] = a;
            if (r != 3)  // next-step chain, overlapped by following rows
                c[r] = coef_from_z(fmaf(K, wave64_sum(a), zb[r]), tg[r]);
        }
    }

    // Epilogue: re-load s (not kept live through the loop) and add dl.
#pragma unroll
    for (int r = 0; r < 4; ++r) {
        const float4* sr = (const float4*)(s + (size_t)(rb + r) * D_);
        const float4 sa = sr[lane], sb = sr[lane + 64];
        float4 oa = {sa.x + dl[r][0], sa.y + dl[r][1],
                     sa.z + dl[r][2], sa.w + dl[r][3]};
        float4 ob = {sb.x + dl[r][4], sb.y + dl[r][5],
                     sb.z + dl[r][6], sb.w + dl[r][7]};
        float4* orow = (float4*)(out + (size_t)(rb + r) * D_);
        orow[lane]      = oa;
        orow[lane + 64] = ob;
    }
}

extern "C" void kernel_launch(void* const* d_in, const int* in_sizes, int n_in,
                              void* d_out, int out_size, void* d_ws, size_t ws_size,
                              hipStream_t stream) {
    const float* s    = (const float*)d_in[0];  // [4096, 512]
    const float* tgt  = (const float*)d_in[1];  // [4096, 1]
    const float* W    = (const float*)d_in[2];  // [1, 512]
    const float* bias = (const float*)d_in[3];  // [1]
    float* out = (float*)d_out;                 // [4096, 512]

    adam_rows_kernel<<<dim3(B_ / 4), dim3(64), 0, stream>>>(s, tgt, W, bias, out);
}

// Round 8
// 91.271 us; speedup vs baseline: 1.3108x; 1.0134x over previous
//
#include <hip/hip_runtime.h>

#define B_ 4096
#define D_ 512
#define STEPS_ 50

// DPP add-reduce step; bound_ctrl=true -> out-of-row source reads 0.
#define DPP_ADD(x, ctrl) \
    ((x) + __int_as_float(__builtin_amdgcn_update_dpp( \
        0, __float_as_int(x), (ctrl), 0xf, 0xf, true)))

// Sum within each 16-lane row; result valid at lane 15 of each row.
__device__ __forceinline__ float row16_sum(float x) {
    x = DPP_ADD(x, 0x111);  // row_shr:1
    x = DPP_ADD(x, 0x112);  // row_shr:2
    x = DPP_ADD(x, 0x114);  // row_shr:4
    x = DPP_ADD(x, 0x118);  // row_shr:8
    return x;
}

// Broadcast lane 16g+15's value to all lanes of group g (one LDS-crossbar op).
__device__ __forceinline__ float grp_bcast15(float x, int vsel) {
    return __int_as_float(__builtin_amdgcn_ds_bpermute(vsel, __float_as_int(x)));
}

// coef = (p - t)*p*(1-p), p = sigmoid(z); p(1-p) = e*p^2 with e = exp(-z).
__device__ __forceinline__ float coef_from_z(float z, float t) {
    const float e = __expf(-z);
    const float q = __builtin_amdgcn_rcpf(1.0f + e);
    return (q - t) * (e * (q * q));
}

// SEGMENTED layout: 4 rows/wave, row r on lanes [16r,16r+16), 32 elems/lane.
// R4/R6/R7 all showed ~200 cy exposed latency PER reduce+sigmoid chain
// regardless of wave count or rotation — so this cuts chains/step 4x -> 1x:
// all 4 rows reduce in ONE DPP tree (row_shr acts within 16-lane rows),
// one vectorized coef chain (lanes 15 mod 16 carry data; trans 8->2/step),
// one ds_bpermute broadcasts each group's coef back. Step-49 chain skipped.
// Lane j of a group owns cols {4j + 64q + i}: per q-chunk a group's 16
// float4s cover 256B contiguous -> coalesced enough, L3-resident anyway.
__global__ __launch_bounds__(64, 1) void adam_rows_kernel(
    const float* __restrict__ s,
    const float* __restrict__ tgt,
    const float* __restrict__ W,
    const float* __restrict__ bias_p,
    float* __restrict__ out)
{
    const int lane = threadIdx.x;          // 0..63
    const int grp  = lane >> 4;            // row within the wave's 4
    const int j    = lane & 15;            // lane within group
    const int row  = blockIdx.x * 4 + grp;
    const int vsel = ((lane & 48) | 15) << 2;   // byte sel of lane 16g+15

    // Lane-indexed An table: An[t] = -(lr*0.1/(1-0.9^(t+1)))/sqrt(0.001/(1-0.999^(t+1)))
    float vAn;
    {
        const float t1 = (float)(lane + 1);
        const float p1 = exp2f(t1 * -0.15200309344505f);    // 0.9^(t+1)
        const float p2 = exp2f(t1 * -0.00144345345258f);    // 0.999^(t+1)
        vAn = (-0.0316227766017f * __builtin_amdgcn_sqrtf(1.0f - p2)) *
              __builtin_amdgcn_rcpf(1.0f - p1);
    }

    const float c_mse = 0x1p-11f;          // 2/B, exact
    const float K     = 2048.0f;           // 1/c_mse
    const float c_l1  = 0x1p-21f;          // 1/(B*D)

    const float4* W4  = (const float4*)W;
    const float4* sr4 = (const float4*)(s + (size_t)row * D_);

    float ws[32], dl[32], M[32], V[32];
#pragma unroll
    for (int q = 0; q < 8; ++q) {
        const float4 w = W4[j + 16 * q];
        ws[4*q+0] = w.x * c_mse; ws[4*q+1] = w.y * c_mse;
        ws[4*q+2] = w.z * c_mse; ws[4*q+3] = w.w * c_mse;
    }

    // zb = s_row.W + b, all 4 rows reduced in one DPP tree.
    float vzb;
    {
        float a0 = 0.0f, a1 = 0.0f, a2 = 0.0f, a3 = 0.0f;
#pragma unroll
        for (int q = 0; q < 8; ++q) {
            const float4 e = sr4[j + 16 * q];
            a0 = fmaf(e.x, ws[4*q+0], a0);
            a1 = fmaf(e.y, ws[4*q+1], a1);
            a2 = fmaf(e.z, ws[4*q+2], a2);
            a3 = fmaf(e.w, ws[4*q+3], a3);
        }
        vzb = fmaf(K, row16_sum((a0 + a1) + (a2 + a3)), bias_p[0]);
    }
    const float vtg = tgt[row];

    float vc;  // per-lane coef (broadcast within group)

    // ---- step 0 peeled: dl == 0 -> L1 term 0; V seeded +1e-30 ----
    {
        const float An0 =
            __int_as_float(__builtin_amdgcn_readlane(__float_as_int(vAn), 0));
        vc = grp_bcast15(coef_from_z(vzb, vtg), vsel);
        float a0 = 0.0f, a1 = 0.0f, a2 = 0.0f, a3 = 0.0f;
#pragma unroll
        for (int k = 0; k < 32; ++k) {
            const float g = vc * ws[k];
            M[k] = g;
            V[k] = fmaf(g, g, 1e-30f);
            dl[k] = (An0 * g) * __builtin_amdgcn_rsqf(V[k]);
            float* acc = (k & 2) ? ((k & 1) ? &a3 : &a2) : ((k & 1) ? &a1 : &a0);
            *acc = fmaf(dl[k], ws[k], *acc);
        }
        const float vz = fmaf(K, row16_sum((a0 + a1) + (a2 + a3)), vzb);
        vc = grp_bcast15(coef_from_z(vz, vtg), vsel);
    }

    // ---- steps 1..49 ----
#pragma unroll 1
    for (int step = 1; step < STEPS_; ++step) {
        const float An =
            __int_as_float(__builtin_amdgcn_readlane(__float_as_int(vAn), step));
        float a0 = 0.0f, a1 = 0.0f, a2 = 0.0f, a3 = 0.0f;
#pragma unroll
        for (int k = 0; k < 32; ++k) {
            const float g = fmaf(vc, ws[k], __builtin_copysignf(c_l1, dl[k]));
            M[k] = fmaf(0.9f,   M[k], g);
            V[k] = fmaf(0.999f, V[k], g * g);
            dl[k] = fmaf(An * M[k], __builtin_amdgcn_rsqf(V[k]), dl[k]);
            float* acc = (k & 2) ? ((k & 1) ? &a3 : &a2) : ((k & 1) ? &a1 : &a0);
            *acc = fmaf(dl[k], ws[k], *acc);
        }
        if (step != STEPS_ - 1) {   // step 49's dot is never consumed
            const float vz = fmaf(K, row16_sum((a0 + a1) + (a2 + a3)), vzb);
            vc = grp_bcast15(coef_from_z(vz, vtg), vsel);
        }
    }

    // Epilogue: re-load s and write x = s + dl.
    float4* orow = (float4*)(out + (size_t)row * D_);
#pragma unroll
    for (int q = 0; q < 8; ++q) {
        const float4 e = sr4[j + 16 * q];
        float4 o = {e.x + dl[4*q+0], e.y + dl[4*q+1],
                    e.z + dl[4*q+2], e.w + dl[4*q+3]};
        orow[j + 16 * q] = o;
    }
}

extern "C" void kernel_launch(void* const* d_in, const int* in_sizes, int n_in,
                              void* d_out, int out_size, void* d_ws, size_t ws_size,
                              hipStream_t stream) {
    const float* s    = (const float*)d_in[0];  // [4096, 512]
    const float* tgt  = (const float*)d_in[1];  // [4096, 1]
    const float* W    = (const float*)d_in[2];  // [1, 512]
    const float* bias = (const float*)d_in[3];  // [1]
    float* out = (float*)d_out;                 // [4096, 512]

    adam_rows_kernel<<<dim3(B_ / 4), dim3(64), 0, stream>>>(s, tgt, W, bias, out);
}